// Round 8
// baseline (103.616 us; speedup 1.0000x reference)
//
#include <hip/hip_runtime.h>
#include <math.h>

// Problem dims (fixed by the reference setup): B=4, C=64, H=512, W=512, fp32.
#define HH 512
#define W4Q 128          // float4 quads per full row
#define IMG (HH * 512)
#define NR 64            // LDS ring: 64 row slots (pow2)
#define RST 41           // quads per slot: 32 data + 8 halo + 1 pad (odd stride)
#define SS 32            // rows per step
#define HALF 256         // output rows per block
#define NSTEP (HALF / SS)

typedef float f32x4 __attribute__((ext_vector_type(4)));

__device__ __forceinline__ f32x4 bc4(float v) { f32x4 r = {v, v, v, v}; return r; }
__device__ __forceinline__ float softplus(float x) {
    return fmaxf(x, 0.0f) + log1pf(expf(-fabsf(x)));
}

__global__ __launch_bounds__(256, 3) void lap3_kernel(const float* __restrict__ u,
                                                      const float* __restrict__ D,
                                                      float* __restrict__ out) {
    // 42 KB window -> 3 resident blocks/CU (12 waves, 3 barrier domains).
    __shared__ f32x4 lds[NR * RST];

    const int bid  = blockIdx.x;            // 2048 = 256 img x 2 row-halves x 4 col-quarters
    const int bc   = bid >> 3;              // image (b*64+c)
    const int cq   = bid & 3;               // column quarter
    const int row0 = ((bid >> 2) & 1) * HALF;
    const int c    = bc & 63;
    const int gq0  = cq * 32;               // global quad base of this quarter

    const float s0 = softplus(D[c]);
    const float s1 = softplus(D[64 + c]);
    const float s2 = softplus(D[128 + c]);
    const float m4c = -4.0f * (s0 + s1 + s2);

    const int t  = threadIdx.x;
    const int q  = t & 31;                  // data quad within quarter
    const int g  = t >> 5;                  // row group 0..7 (4 rows each)
    const int wq = q + 4;                   // window quad index (4..35)

    const f32x4* __restrict__ img4 =
        reinterpret_cast<const f32x4*>(u) + (size_t)bc * (IMG / 4);
    f32x4* __restrict__ out4 =
        reinterpret_cast<f32x4*>(out) + (size_t)bc * (IMG / 4);

    // Stage one 32-row band (40 quads/row, horizontal clamp MATERIALIZED):
    // 1280 quad-loads, 5 per thread. Returns via direct LDS write.
    auto stage_now = [&](int vrow0) {
#pragma unroll
        for (int j = 0; j < 5; ++j) {
            const int idx = j * 256 + t;
            const int rr  = idx / 40;       // magic-mul div
            const int col = idx - rr * 40;
            const int vrow = vrow0 + rr;
            const int crow = min(max(vrow, 0), HH - 1);
            const int vgq  = gq0 - 4 + col; // virtual global quad
            const int gqc  = min(max(vgq, 0), W4Q - 1);
            f32x4 v = img4[crow * W4Q + gqc];
            if (vgq < 0)       v = bc4(v.x);   // left edge-replicate
            if (vgq > W4Q - 1) v = bc4(v.w);   // right edge-replicate
            lds[(vrow & (NR - 1)) * RST + col] = v;
        }
    };

    // Prologue: virtual rows [row0-16, row0+48)
    stage_now(row0 - 16);
    stage_now(row0 + 16);
    __syncthreads();

#pragma unroll 1
    for (int step = 0; step < NSTEP; ++step) {
        const int h0 = row0 + step * SS;
        const bool do_stage = (step < NSTEP - 1);

        // async-split staging: issue next band's global loads NOW,
        // LDS-write after the post-compute barrier.
        f32x4 gbuf[5];
        int gaddr[5];
        if (do_stage) {
            const int vrow0 = h0 + 48;
#pragma unroll
            for (int j = 0; j < 5; ++j) {
                const int idx = j * 256 + t;
                const int rr  = idx / 40;
                const int col = idx - rr * 40;
                const int vrow = vrow0 + rr;
                const int crow = min(vrow, HH - 1);   // only bottom clamp possible here
                const int vgq  = gq0 - 4 + col;
                const int gqc  = min(max(vgq, 0), W4Q - 1);
                f32x4 v = img4[crow * W4Q + gqc];
                if (vgq < 0)       v = bc4(v.x);
                if (vgq > W4Q - 1) v = bc4(v.w);
                gbuf[j] = v;
                gaddr[j] = (vrow & (NR - 1)) * RST + col;
            }
        }

        // ---- compute 4-row column run, entirely from LDS, zero boundary logic
        const int hr = h0 + g * 4;
        f32x4 C[6];                          // rows hr-1 .. hr+4
#pragma unroll
        for (int k = 0; k < 6; ++k)
            C[k] = lds[((hr - 1 + k) & (NR - 1)) * RST + wq];
        f32x4 U4[3], D4v[3];
#pragma unroll
        for (int k = 0; k < 3; ++k)
            U4[k] = lds[((hr - 4 + k) & (NR - 1)) * RST + wq];
#pragma unroll
        for (int k = 0; k < 3; ++k)
            D4v[k] = lds[((hr + 5 + k) & (NR - 1)) * RST + wq];

#pragma unroll
        for (int r = 0; r < 4; ++r) {
            const int rs = ((hr + r) & (NR - 1)) * RST;
            const f32x4 l4  = lds[rs + wq - 1];
            const f32x4 r4  = lds[rs + wq + 1];
            const f32x4 l16 = lds[rs + wq - 4];
            const f32x4 r16 = lds[rs + wq + 4];
            const f32x4 u16 = lds[((hr + r - 16) & (NR - 1)) * RST + wq];
            const f32x4 d16 = lds[((hr + r + 16) & (NR - 1)) * RST + wq];

            const f32x4 cc = C[r + 1], up1 = C[r], dn1 = C[r + 2];
            const f32x4 u4 = (r < 3) ? U4[r] : C[0];        // row hr+r-4
            const f32x4 d4 = (r == 0) ? C[5] : D4v[r - 1];  // row hr+r+4

            const f32x4 l1 = { l4.w, cc.x, cc.y, cc.z };
            const f32x4 r1 = { cc.y, cc.z, cc.w, r4.x };

            const f32x4 d1s  = (up1 + dn1) + (l1 + r1);
            const f32x4 d4s  = (u4 + d4) + (l4 + r4);
            const f32x4 d16s = (u16 + d16) + (l16 + r16);

            f32x4 o;
#pragma unroll
            for (int j = 0; j < 4; ++j) {
                float acc = m4c * cc[j];
                acc = fmaf(s0, d1s[j], acc);
                acc = fmaf(s1, d4s[j], acc);
                acc = fmaf(s2, d16s[j], acc);
                o[j] = acc;
            }
            __builtin_nontemporal_store(o, out4 + (hr + r) * W4Q + gq0 + q);
        }

        __syncthreads();            // all reads of to-be-overwritten rows done
        if (do_stage) {
#pragma unroll
            for (int j = 0; j < 5; ++j)
                lds[gaddr[j]] = gbuf[j];
        }
        __syncthreads();            // staged rows visible for next step
    }
}

extern "C" void kernel_launch(void* const* d_in, const int* in_sizes, int n_in,
                              void* d_out, int out_size, void* d_ws, size_t ws_size,
                              hipStream_t stream) {
    const float* u = (const float*)d_in[0];
    const float* D = (const float*)d_in[1];
    float* out = (float*)d_out;

    lap3_kernel<<<2048, 256, 0, stream>>>(u, D, out);
}

// Round 9
// 86.921 us; speedup vs baseline: 1.1921x; 1.1921x over previous
//
#include <hip/hip_runtime.h>
#include <math.h>

// Problem dims (fixed by the reference setup): B=4, C=64, H=512, W=512, fp32.
#define HH 512
#define W4Q 128          // float4 quads per row
#define IMG (HH * 512)
#define NR 64            // LDS ring: 64 row slots (pow2)
#define RST 129          // quads per slot (+1 pad -> odd stride, conflict-free)
#define SS 16            // rows per step (writes never collide with reads)
#define HALF 256         // output rows per block
#define NSTEP (HALF / SS)   // 16

typedef float f32x4 __attribute__((ext_vector_type(4)));

__device__ __forceinline__ f32x4 bc4(float v) { f32x4 r = {v, v, v, v}; return r; }
__device__ __forceinline__ float softplus(float x) {
    return fmaxf(x, 0.0f) + log1pf(expf(-fabsf(x)));
}

__global__ __launch_bounds__(512) void lap3_kernel(const float* __restrict__ u,
                                                   const float* __restrict__ D,
                                                   float* __restrict__ out) {
    // 132 KB rolling row window (64 rows x 129 quads). One block per CU.
    __shared__ f32x4 lds[NR * RST];

    const int b    = blockIdx.x;        // 512 blocks = 256 images x 2 halves
    const int bc   = b >> 1;            // image index (b*64 + c)
    const int row0 = (b & 1) * HALF;    // output rows [row0, row0+256)
    const int c    = bc & 63;

    const float s0 = softplus(D[c]);
    const float s1 = softplus(D[64 + c]);
    const float s2 = softplus(D[128 + c]);
    const float m4c = -4.0f * (s0 + s1 + s2);

    const int t  = threadIdx.x;
    const int q  = t & 127;             // quad column (both compute & staging)
    const int g  = t >> 7;              // compute: row group 0..3 (4 rows each)
    const int sr = t >> 7;              // staging: row offset 0..3 (rows sr+4j)

    const f32x4* __restrict__ img4 =
        reinterpret_cast<const f32x4*>(u) + (size_t)bc * (IMG / 4);
    f32x4* __restrict__ out4 =
        reinterpret_cast<f32x4*>(out) + (size_t)bc * (IMG / 4);

    // ---- prologue: stage virtual rows [row0-16, row0+32) (48 rows, clamped).
    // Vertical clamping is materialized here; compute has no vertical logic.
#pragma unroll
    for (int j = 0; j < 12; ++j) {
        const int vrow = row0 - 16 + sr + 4 * j;
        const int crow = min(max(vrow, 0), HH - 1);
        lds[(vrow & (NR - 1)) * RST + q] = img4[crow * W4Q + q];
    }
    __syncthreads();

    // horizontal boundary handling (validated R4/R7 scheme)
    const int qm1 = max(q - 1, 0), qp1 = min(q + 1, W4Q - 1);
    const int qm4 = max(q - 4, 0), qp4 = min(q + 4, W4Q - 1);
    const bool pl4 = (q == 0), pr4 = (q == W4Q - 1);
    const bool pl16 = (q < 4), pr16 = (q > W4Q - 5);

#pragma unroll 1
    for (int step = 0; step < NSTEP; ++step) {
        const int h0 = row0 + step * SS;
        const bool do_stage = (step < NSTEP - 1);

        // async-split staging: issue next band's (rows [h0+32, h0+48))
        // global loads NOW; ds_write after this wave's own compute.
        // Write slots are rows [h0+32,h0+48) & 63 — disjoint from the read
        // span [h0-16, h0+32), so no pre-write barrier is needed.
        f32x4 gbuf[4];
        if (do_stage) {
#pragma unroll
            for (int j = 0; j < 4; ++j) {
                const int vrow = h0 + 32 + sr + 4 * j;
                const int crow = min(vrow, HH - 1);   // only bottom clamp here
                gbuf[j] = img4[crow * W4Q + q];
            }
        }

        // ---- compute 4-row column run, entirely from LDS
        const int hr = h0 + g * 4;
        f32x4 C[6];                          // rows hr-1 .. hr+4
#pragma unroll
        for (int k = 0; k < 6; ++k)
            C[k] = lds[((hr - 1 + k) & (NR - 1)) * RST + q];
        f32x4 U4[3], D4v[3];                 // d=4 extras
#pragma unroll
        for (int k = 0; k < 3; ++k)
            U4[k] = lds[((hr - 4 + k) & (NR - 1)) * RST + q];
#pragma unroll
        for (int k = 0; k < 3; ++k)
            D4v[k] = lds[((hr + 5 + k) & (NR - 1)) * RST + q];

#pragma unroll
        for (int r = 0; r < 4; ++r) {
            const int rs = ((hr + r) & (NR - 1)) * RST;
            f32x4 l4 = lds[rs + qm1];  if (pl4)  l4 = bc4(l4.x);
            f32x4 r4 = lds[rs + qp1];  if (pr4)  r4 = bc4(r4.w);
            f32x4 l16 = lds[rs + qm4]; if (pl16) l16 = bc4(l16.x);
            f32x4 r16 = lds[rs + qp4]; if (pr16) r16 = bc4(r16.w);
            const f32x4 u16 = lds[((hr + r - 16) & (NR - 1)) * RST + q];
            const f32x4 d16 = lds[((hr + r + 16) & (NR - 1)) * RST + q];

            const f32x4 cc = C[r + 1], up1 = C[r], dn1 = C[r + 2];
            const f32x4 u4 = (r < 3) ? U4[r] : C[0];        // row hr+r-4
            const f32x4 d4 = (r == 0) ? C[5] : D4v[r - 1];  // row hr+r+4

            // d=1 horizontal from registers (l4.w / r4.x are the +/-1 px)
            const f32x4 l1 = { l4.w, cc.x, cc.y, cc.z };
            const f32x4 r1 = { cc.y, cc.z, cc.w, r4.x };

            const f32x4 d1s  = (up1 + dn1) + (l1 + r1);
            const f32x4 d4s  = (u4 + d4) + (l4 + r4);
            const f32x4 d16s = (u16 + d16) + (l16 + r16);

            f32x4 o;
#pragma unroll
            for (int j = 0; j < 4; ++j) {
                float acc = m4c * cc[j];
                acc = fmaf(s0, d1s[j], acc);
                acc = fmaf(s1, d4s[j], acc);
                acc = fmaf(s2, d16s[j], acc);
                o[j] = acc;
            }
            __builtin_nontemporal_store(o, out4 + (hr + r) * W4Q + q);
        }

        // each wave writes its staged rows as soon as ITS compute is done
        if (do_stage) {
#pragma unroll
            for (int j = 0; j < 4; ++j) {
                const int vrow = h0 + 32 + sr + 4 * j;
                lds[(vrow & (NR - 1)) * RST + q] = gbuf[j];
            }
        }
        __syncthreads();   // single barrier: this step's reads done AND
                           // staged rows visible before next step
    }
}

extern "C" void kernel_launch(void* const* d_in, const int* in_sizes, int n_in,
                              void* d_out, int out_size, void* d_ws, size_t ws_size,
                              hipStream_t stream) {
    const float* u = (const float*)d_in[0];
    const float* D = (const float*)d_in[1];
    float* out = (float*)d_out;

    lap3_kernel<<<512, 512, 0, stream>>>(u, D, out);
}